// Round 6
// baseline (31.705 us; speedup 1.0000x reference)
//
#include <hip/hip_runtime.h>

#define BB 32
#define NN 1024
#define DD 256

// ---------------- fused kernel, register-resident rows ----------------
// 1024 blocks x 256 threads = exactly 4 blocks/CU x 256 CUs. Launched as a
// REGULAR kernel: grid == max co-residency and the GPU runs nothing else,
// so all workgroups are resident and the per-slice spin barrier is safe.
// (Rounds 1-5 used hipLaunchCooperativeKernel; kernel-side improvements
// moved rocprof dispatch time 280->108us with bench time flat at ~27us ->
// the ~12us residual is launch-path overhead, i.e. the cooperative launch.)
// Each wave holds 16 rows in registers across the sync (pinned by opaque
// asm + memory clobber). Producers atomicAdd straight into fsum[slice][256];
// consumers read ONE coherent float per thread.
#define NSLICE 64                 // 2 tensors * 32 batches
#define BPS 16                    // blocks per slice
#define NBLOCKS (NSLICE * BPS)    // 1024
#define RPB 64                    // rows per block
#define RPW 16                    // rows per wave (4 waves/block)

// ws layout: [64 counters, 64B apart -> 4 KB][fsum 64 KB]; memset 0 each launch
#define WS_CTR_STRIDE 16          // u32s per counter line (64 B)
#define WS_CTR_BYTES  (NSLICE * WS_CTR_STRIDE * 4)
#define WS_FSUM_BYTES (NSLICE * DD * 4)
#define WS_NEEDED     ((size_t)WS_CTR_BYTES + WS_FSUM_BYTES)

__global__ __launch_bounds__(256, 4)
void fused_kernel(const float* __restrict__ x, const float* __restrict__ y,
                  unsigned int* __restrict__ ctr,  // [NSLICE] stride 16 u32
                  float* __restrict__ fsum,        // [NSLICE][DD]
                  float* __restrict__ out) {
    const int bid   = blockIdx.x;
    const int slice = bid / BPS;        // 0..31 = x batches, 32..63 = y batches
    const int chunk = bid % BPS;
    const int t     = slice >> 5;       // 0 = x rows, 1 = y rows
    const int b     = slice & 31;
    const int lane  = threadIdx.x & 63;
    const int wave  = threadIdx.x >> 6; // 0..3
    const int d     = threadIdx.x;      // 0..255

    const int row0 = chunk * RPB + wave * RPW;
    const float4* srcv = reinterpret_cast<const float4*>(
        (t == 0 ? x : y) + (size_t)b * NN * DD) + (size_t)row0 * (DD / 4) + lane;

    // ---- phase 1: stream 16 rows into registers, column-sum on the way ----
    float4 v[RPW];
    float4 p = make_float4(0.f, 0.f, 0.f, 0.f);
    #pragma unroll
    for (int r = 0; r < RPW; ++r) {
        v[r] = srcv[(size_t)r * (DD / 4)];
        p.x += v[r].x; p.y += v[r].y; p.z += v[r].z; p.w += v[r].w;
    }

    // Pin rows: opaque origin + memory clobber so loads can't sink past here
    // and the pinned values must be carried across the sync.
    #pragma unroll
    for (int r = 0; r < RPW; ++r) {
        asm volatile("" : "+v"(v[r].x), "+v"(v[r].y), "+v"(v[r].z), "+v"(v[r].w)
                         :: "memory");
    }
    __builtin_amdgcn_sched_barrier(0);

    __shared__ float lds[4][DD];        // 4 KB
    *reinterpret_cast<float4*>(&lds[wave][lane * 4]) = p;
    __syncthreads();
    float ps = lds[0][d] + lds[1][d] + lds[2][d] + lds[3][d];

    // One device-scope fp32 atomicAdd per thread into the FINAL sum.
    __hip_atomic_fetch_add(&fsum[(size_t)slice * DD + d], ps,
                           __ATOMIC_RELAXED, __HIP_MEMORY_SCOPE_AGENT);

    // ---- per-slice sync: every wave drains its add at the barrier, then
    // thread 0 publishes arrival (release) and waits for the opposite slice.
    const int opp = slice ^ 32;         // flip tensor, same batch
    __syncthreads();                    // vmcnt(0) drain: block's adds complete
    if (threadIdx.x == 0) {
        __hip_atomic_fetch_add(&ctr[slice * WS_CTR_STRIDE], 1u,
                               __ATOMIC_RELEASE, __HIP_MEMORY_SCOPE_AGENT);
        while (__hip_atomic_load(&ctr[opp * WS_CTR_STRIDE],
                   __ATOMIC_ACQUIRE, __HIP_MEMORY_SCOPE_AGENT) < (unsigned)BPS)
            __builtin_amdgcn_s_sleep(2);
    }
    __syncthreads();

    // ---- phase 2: one coherent load per thread, broadcast via LDS, dots ----
    float s = __hip_atomic_load(&fsum[(size_t)opp * DD + d],
                                __ATOMIC_ACQUIRE, __HIP_MEMORY_SCOPE_AGENT);
    lds[0][d] = s;
    __syncthreads();

    const float4 sv = *reinterpret_cast<const float4*>(&lds[0][lane * 4]);

    // t==0 (x rows): colsum -> out[b][1024+n]; t==1 (y rows): rowsum -> out[b][m]
    float* outp = out + (size_t)b * 2048 + (t == 0 ? 1024 : 0) + row0;
    #pragma unroll
    for (int r = 0; r < RPW; ++r) {
        float dv = v[r].x * sv.x + v[r].y * sv.y + v[r].z * sv.z + v[r].w * sv.w;
        #pragma unroll
        for (int off = 32; off >= 1; off >>= 1)
            dv += __shfl_down(dv, off, 64);
        if (lane == 0) outp[r] = dv;
    }
}

// ---------------- fallback: proven two-kernel path ----------------
#define SPLIT 8
#define CHUNK (NN / SPLIT)

__global__ void colsum_partial_kernel(const float* __restrict__ x,
                                      const float* __restrict__ y,
                                      float* __restrict__ partial) {
    int bid = blockIdx.x;
    int t   = bid / (BB * SPLIT);
    int rem = bid % (BB * SPLIT);
    int b   = rem / SPLIT;
    int s   = rem % SPLIT;
    int d   = threadIdx.x;

    const float* src = (t == 0 ? x : y)
                     + (size_t)b * NN * DD + (size_t)s * CHUNK * DD + d;

    float a0 = 0.f, a1 = 0.f, a2 = 0.f, a3 = 0.f;
    #pragma unroll 4
    for (int n = 0; n < CHUNK; n += 4) {
        a0 += src[(size_t)(n + 0) * DD];
        a1 += src[(size_t)(n + 1) * DD];
        a2 += src[(size_t)(n + 2) * DD];
        a3 += src[(size_t)(n + 3) * DD];
    }
    partial[(((size_t)t * SPLIT + s) * BB + b) * DD + d] = (a0 + a1) + (a2 + a3);
}

#define RCHUNKS 16
#define ROWS_PER_BLOCK 64

__global__ void dots_kernel(const float* __restrict__ x,
                            const float* __restrict__ y,
                            const float* __restrict__ partial,
                            float* __restrict__ out) {
    int bid = blockIdx.x;
    int rc  = bid % RCHUNKS;
    int bt  = bid / RCHUNKS;
    int t   = bt & 1;
    int b   = bt >> 1;
    int d   = threadIdx.x;

    __shared__ float ssum[DD];
    {
        const float* p = partial + ((size_t)t * SPLIT * BB + b) * DD + d;
        float s = 0.f;
        #pragma unroll
        for (int k = 0; k < SPLIT; ++k) s += p[(size_t)k * BB * DD];
        ssum[d] = s;
    }
    __syncthreads();

    int lane = threadIdx.x & 63;
    int wave = threadIdx.x >> 6;

    float4 sv = *reinterpret_cast<const float4*>(&ssum[lane * 4]);
    const float* data = (t == 0 ? y : x) + (size_t)b * NN * DD;
    float* outp = out + (size_t)b * 2048 + (size_t)t * 1024;

    int r0 = rc * ROWS_PER_BLOCK + wave * 16;
    #pragma unroll 4
    for (int r = 0; r < 16; ++r) {
        int row = r0 + r;
        float4 w = *reinterpret_cast<const float4*>(&data[(size_t)row * DD + lane * 4]);
        float dotv = w.x * sv.x + w.y * sv.y + w.z * sv.z + w.w * sv.w;
        #pragma unroll
        for (int off = 32; off >= 1; off >>= 1)
            dotv += __shfl_down(dotv, off, 64);
        if (lane == 0) outp[row] = dotv;
    }
}

extern "C" void kernel_launch(void* const* d_in, const int* in_sizes, int n_in,
                              void* d_out, int out_size, void* d_ws, size_t ws_size,
                              hipStream_t stream) {
    const float* x = (const float*)d_in[0];
    const float* y = (const float*)d_in[1];
    float* out     = (float*)d_out;

    // Regular launch is safe only if >=4 blocks/CU fit (grid 1024 = 4*256 CU
    // -> all workgroups co-resident for the spin barrier). Gate on that.
    static int use_fused = -1;
    if (use_fused < 0) {
        int nb = 0;
        hipError_t e = hipOccupancyMaxActiveBlocksPerMultiprocessor(
            &nb, (const void*)fused_kernel, 256, 0);
        use_fused = (e == hipSuccess && nb >= 4 && ws_size >= WS_NEEDED) ? 1 : 0;
    }

    if (use_fused) {
        unsigned int* ctr = (unsigned int*)d_ws;
        float* fsum       = (float*)((char*)d_ws + WS_CTR_BYTES);
        hipMemsetAsync(d_ws, 0, WS_NEEDED, stream);   // zero counters + fsum
        fused_kernel<<<dim3(NBLOCKS), dim3(256), 0, stream>>>(x, y, ctr, fsum, out);
        return;
    }

    float* partial = (float*)d_ws;      // fallback layout: 512 KB at ws+0
    colsum_partial_kernel<<<2 * BB * SPLIT, 256, 0, stream>>>(x, y, partial);
    dots_kernel<<<BB * 2 * RCHUNKS, 256, 0, stream>>>(x, y, partial, out);
}

// Round 7
// 27.130 us; speedup vs baseline: 1.1686x; 1.1686x over previous
//
#include <hip/hip_runtime.h>

#define BB 32
#define NN 1024
#define DD 256

// ---------------- fused kernel, register-resident rows ----------------
// 1024 blocks x 256 threads, co-resident via cooperative launch.
// Round-7 fixes target the sync cost exposed by rocprof (dispatch ~108us,
// VALUBusy 1.6%, 325 GB/s -> kernel idles in the spin barrier):
//  1. Spin with RELAXED loads. Agent-scope ACQUIRE loads lower to
//     load+buffer_inv on gfx950; polling with them = continuous L1/L2
//     invalidation storm that also wrecks concurrent phase-1 streaming.
//     Ordering is recovered by the single acquire load of fsum afterwards.
//  2. Interleaved pair ordering: a batch's x-blocks and y-blocks are
//     dispatch-adjacent (slice pairs launch together), instead of the
//     x-side (bids 0-511) waiting for the entire y-side (bids 512-1023).
#define NSLICE 64                 // 2 tensors * 32 batches
#define BPS 16                    // blocks per slice
#define NBLOCKS (NSLICE * BPS)    // 1024
#define RPB 64                    // rows per block
#define RPW 16                    // rows per wave (4 waves/block)

// ws layout: [64 counters, 64B apart -> 4 KB][fsum 64 KB]; memset 0 each launch
#define WS_CTR_STRIDE 16          // u32s per counter line (64 B)
#define WS_CTR_BYTES  (NSLICE * WS_CTR_STRIDE * 4)
#define WS_FSUM_BYTES (NSLICE * DD * 4)
#define WS_NEEDED     ((size_t)WS_CTR_BYTES + WS_FSUM_BYTES)

__global__ __launch_bounds__(256, 4)
void fused_kernel(const float* __restrict__ x, const float* __restrict__ y,
                  unsigned int* __restrict__ ctr,  // [NSLICE] stride 16 u32
                  float* __restrict__ fsum,        // [NSLICE][DD]
                  float* __restrict__ out) {
    const int bid   = blockIdx.x;
    // Interleaved mapping: batch-major, tensor inner -> paired slices are
    // adjacent in dispatch order (bids b*32+0..15 = x[b], b*32+16..31 = y[b]).
    const int b     = bid >> 5;          // 0..31
    const int t     = (bid >> 4) & 1;    // 0 = x rows, 1 = y rows
    const int chunk = bid & 15;          // 0..15
    const int slice = t * 32 + b;
    const int lane  = threadIdx.x & 63;
    const int wave  = threadIdx.x >> 6;  // 0..3
    const int d     = threadIdx.x;       // 0..255

    const int row0 = chunk * RPB + wave * RPW;
    const float4* srcv = reinterpret_cast<const float4*>(
        (t == 0 ? x : y) + (size_t)b * NN * DD) + (size_t)row0 * (DD / 4) + lane;

    // ---- phase 1: stream 16 rows into registers, column-sum on the way ----
    float4 v[RPW];
    float4 p = make_float4(0.f, 0.f, 0.f, 0.f);
    #pragma unroll
    for (int r = 0; r < RPW; ++r) {
        v[r] = srcv[(size_t)r * (DD / 4)];
        p.x += v[r].x; p.y += v[r].y; p.z += v[r].z; p.w += v[r].w;
    }

    // Pin rows: opaque origin + memory clobber so loads can't sink past here
    // and the pinned values must be carried across the sync.
    #pragma unroll
    for (int r = 0; r < RPW; ++r) {
        asm volatile("" : "+v"(v[r].x), "+v"(v[r].y), "+v"(v[r].z), "+v"(v[r].w)
                         :: "memory");
    }
    __builtin_amdgcn_sched_barrier(0);

    __shared__ float lds[4][DD];        // 4 KB
    *reinterpret_cast<float4*>(&lds[wave][lane * 4]) = p;
    __syncthreads();
    float ps = lds[0][d] + lds[1][d] + lds[2][d] + lds[3][d];

    // One device-scope fp32 atomicAdd per thread into the FINAL sum.
    __hip_atomic_fetch_add(&fsum[(size_t)slice * DD + d], ps,
                           __ATOMIC_RELAXED, __HIP_MEMORY_SCOPE_AGENT);

    // ---- per-slice sync: publish arrival (release), relaxed-poll partner ----
    const int opp = slice ^ 32;         // flip tensor, same batch
    __syncthreads();                    // block's adds issued before arrival
    if (threadIdx.x == 0) {
        __hip_atomic_fetch_add(&ctr[slice * WS_CTR_STRIDE], 1u,
                               __ATOMIC_RELEASE, __HIP_MEMORY_SCOPE_AGENT);
        // RELAXED poll: no per-iteration cache invalidate. The acquire load
        // of fsum below provides the ordering once the count is reached.
        while (__hip_atomic_load(&ctr[opp * WS_CTR_STRIDE],
                   __ATOMIC_RELAXED, __HIP_MEMORY_SCOPE_AGENT) < (unsigned)BPS)
            __builtin_amdgcn_s_sleep(2);
    }
    __syncthreads();

    // ---- phase 2: one coherent (acquire) load per thread, LDS broadcast ----
    float s = __hip_atomic_load(&fsum[(size_t)opp * DD + d],
                                __ATOMIC_ACQUIRE, __HIP_MEMORY_SCOPE_AGENT);
    lds[0][d] = s;
    __syncthreads();

    const float4 sv = *reinterpret_cast<const float4*>(&lds[0][lane * 4]);

    // t==0 (x rows): colsum -> out[b][1024+n]; t==1 (y rows): rowsum -> out[b][m]
    float* outp = out + (size_t)b * 2048 + (t == 0 ? 1024 : 0) + row0;
    #pragma unroll
    for (int r = 0; r < RPW; ++r) {
        float dv = v[r].x * sv.x + v[r].y * sv.y + v[r].z * sv.z + v[r].w * sv.w;
        #pragma unroll
        for (int off = 32; off >= 1; off >>= 1)
            dv += __shfl_down(dv, off, 64);
        if (lane == 0) outp[r] = dv;
    }
}

// ---------------- fallback: proven two-kernel path ----------------
#define SPLIT 8
#define CHUNK (NN / SPLIT)

__global__ void colsum_partial_kernel(const float* __restrict__ x,
                                      const float* __restrict__ y,
                                      float* __restrict__ partial) {
    int bid = blockIdx.x;
    int t   = bid / (BB * SPLIT);
    int rem = bid % (BB * SPLIT);
    int b   = rem / SPLIT;
    int s   = rem % SPLIT;
    int d   = threadIdx.x;

    const float* src = (t == 0 ? x : y)
                     + (size_t)b * NN * DD + (size_t)s * CHUNK * DD + d;

    float a0 = 0.f, a1 = 0.f, a2 = 0.f, a3 = 0.f;
    #pragma unroll 4
    for (int n = 0; n < CHUNK; n += 4) {
        a0 += src[(size_t)(n + 0) * DD];
        a1 += src[(size_t)(n + 1) * DD];
        a2 += src[(size_t)(n + 2) * DD];
        a3 += src[(size_t)(n + 3) * DD];
    }
    partial[(((size_t)t * SPLIT + s) * BB + b) * DD + d] = (a0 + a1) + (a2 + a3);
}

#define RCHUNKS 16
#define ROWS_PER_BLOCK 64

__global__ void dots_kernel(const float* __restrict__ x,
                            const float* __restrict__ y,
                            const float* __restrict__ partial,
                            float* __restrict__ out) {
    int bid = blockIdx.x;
    int rc  = bid % RCHUNKS;
    int bt  = bid / RCHUNKS;
    int t   = bt & 1;
    int b   = bt >> 1;
    int d   = threadIdx.x;

    __shared__ float ssum[DD];
    {
        const float* p = partial + ((size_t)t * SPLIT * BB + b) * DD + d;
        float s = 0.f;
        #pragma unroll
        for (int k = 0; k < SPLIT; ++k) s += p[(size_t)k * BB * DD];
        ssum[d] = s;
    }
    __syncthreads();

    int lane = threadIdx.x & 63;
    int wave = threadIdx.x >> 6;

    float4 sv = *reinterpret_cast<const float4*>(&ssum[lane * 4]);
    const float* data = (t == 0 ? y : x) + (size_t)b * NN * DD;
    float* outp = out + (size_t)b * 2048 + (size_t)t * 1024;

    int r0 = rc * ROWS_PER_BLOCK + wave * 16;
    #pragma unroll 4
    for (int r = 0; r < 16; ++r) {
        int row = r0 + r;
        float4 w = *reinterpret_cast<const float4*>(&data[(size_t)row * DD + lane * 4]);
        float dotv = w.x * sv.x + w.y * sv.y + w.z * sv.z + w.w * sv.w;
        #pragma unroll
        for (int off = 32; off >= 1; off >>= 1)
            dotv += __shfl_down(dotv, off, 64);
        if (lane == 0) outp[row] = dotv;
    }
}

extern "C" void kernel_launch(void* const* d_in, const int* in_sizes, int n_in,
                              void* d_out, int out_size, void* d_ws, size_t ws_size,
                              hipStream_t stream) {
    const float* x = (const float*)d_in[0];
    const float* y = (const float*)d_in[1];
    float* out     = (float*)d_out;

    static int use_coop = -1;
    if (use_coop < 0) {
        int nb = 0;
        hipError_t e = hipOccupancyMaxActiveBlocksPerMultiprocessor(
            &nb, (const void*)fused_kernel, 256, 0);
        use_coop = (e == hipSuccess && nb >= 4 && ws_size >= WS_NEEDED) ? 1 : 0;
    }

    if (use_coop) {
        unsigned int* ctr = (unsigned int*)d_ws;
        float* fsum       = (float*)((char*)d_ws + WS_CTR_BYTES);
        hipMemsetAsync(d_ws, 0, WS_NEEDED, stream);   // zero counters + fsum
        void* args[] = { (void*)&x, (void*)&y, (void*)&ctr,
                         (void*)&fsum, (void*)&out };
        hipError_t e = hipLaunchCooperativeKernel(
            (const void*)fused_kernel, dim3(NBLOCKS), dim3(256), args, 0, stream);
        if (e == hipSuccess) return;
        use_coop = 0;                   // cooperative path unavailable: fall back
    }

    float* partial = (float*)d_ws;      // fallback layout: 512 KB at ws+0
    colsum_partial_kernel<<<2 * BB * SPLIT, 256, 0, stream>>>(x, y, partial);
    dots_kernel<<<BB * 2 * RCHUNKS, 256, 0, stream>>>(x, y, partial, out);
}